// Round 10
// baseline (496.403 us; speedup 1.0000x reference)
//
#include <hip/hip_runtime.h>
#include <math.h>

#define S 512
#define B 128
#define T 256
#define NB 16          // batches per block
#define NTH 256
#define FR 272         // ftile row stride (floats): 4m+4grp mod 32 -> 2-way max (free)
#define LOG2E 1.44269504f
#define LN2 0.69314718f

typedef __fp16 h2v __attribute__((ext_vector_type(2)));
typedef __fp16 h8 __attribute__((ext_vector_type(8)));
typedef float f32x4 __attribute__((ext_vector_type(4)));

#if __has_builtin(__builtin_amdgcn_exp2f)
#define EXP2(x) __builtin_amdgcn_exp2f(x)
#else
#define EXP2(x) exp2f(x)
#endif
#if __has_builtin(__builtin_amdgcn_logf)
#define LOG2F(x) __builtin_amdgcn_logf(x)
#else
#define LOG2F(x) __log2f(x)
#endif

#define AS1 __attribute__((address_space(1)))
#define AS3 __attribute__((address_space(3)))
// LDS-drain barrier only (DMA ring stays in flight; counted vmcnt separately)
#define BAR() do { asm volatile("s_waitcnt lgkmcnt(0)" ::: "memory"); __builtin_amdgcn_s_barrier(); } while (0)

// exact x * 2^n (n in [-126,127])
__device__ __forceinline__ float mul2n(float x, int n) {
    return x * __builtin_bit_cast(float, (n + 127) << 23);
}

__global__ __launch_bounds__(NTH, 1) void crf_fwd(
    const float* __restrict__ feats,
    const int*   __restrict__ tags,
    const int*   __restrict__ mask,
    const float* __restrict__ start_t,
    const float* __restrict__ end_t,
    const float* __restrict__ trans,
    float*       __restrict__ out)
{
    const int tid = threadIdx.x;
    const int l   = tid & 63;
    const int w   = tid >> 6;     // wave 0..3: owns output states [64w, 64w+64)
    const int m   = l & 15;       // this thread's batch (M/N lane mapping)
    const int grp = l >> 4;       // 0..3
    const int b0  = blockIdx.x * NB;

    // qfrag: Q packed in MFMA B-fragment order (verified in R9)
    __shared__ __attribute__((aligned(16))) __fp16 qfrag[2][8][64][8];     // 16 KB
    __shared__ __attribute__((aligned(16))) float ftile[4][NB][FR];        // 69.6 KB DMA ring
    __shared__ int msk16[S];
    __shared__ __attribute__((aligned(16))) float redq[2][NB][4];
    __shared__ __attribute__((aligned(16))) float redi[NB][4];
    __shared__ __attribute__((aligned(16))) float redF[NB][4];
    __shared__ __attribute__((aligned(16))) float redS[NB][4];
    __shared__ float redg[NB][16], redm[NB][16];
    __shared__ float goldv[NB];
    __shared__ __attribute__((aligned(16))) float endf[T];

    // ---- prime DMA ring: tiles 1..4 (slot tn&3), one full batch-row per instruction
    #pragma unroll
    for (int tn = 1; tn <= 4; ++tn) {
        #pragma unroll
        for (int qq = 0; qq < 4; ++qq) {
            const int mr = 4 * qq + w;
            const float* src = feats + ((size_t)tn * B + b0 + mr) * T + l * 4;
            __builtin_amdgcn_global_load_lds((const AS1 void*)src,
                                             (AS3 void*)&ftile[tn & 3][mr][l * 4], 16, 0, 0);
        }
    }

    if (tid < T) endf[tid] = end_t[tid];

    // ---- mask bits: msk16[t] bit m = mask[t][b0+m]
    #pragma unroll
    for (int c = 0; c < 2; ++c) {
        const int t = tid + 256 * c;
        const int4 ma = *(const int4*)&mask[(size_t)t * B + b0];
        const int4 mb = *(const int4*)&mask[(size_t)t * B + b0 + 4];
        const int4 mcq = *(const int4*)&mask[(size_t)t * B + b0 + 8];
        const int4 md = *(const int4*)&mask[(size_t)t * B + b0 + 12];
        const int bits = (ma.x & 1) | ((ma.y & 1) << 1) | ((ma.z & 1) << 2) | ((ma.w & 1) << 3)
                       | ((mb.x & 1) << 4) | ((mb.y & 1) << 5) | ((mb.z & 1) << 6) | ((mb.w & 1) << 7)
                       | ((mcq.x & 1) << 8) | ((mcq.y & 1) << 9) | ((mcq.z & 1) << 10) | ((mcq.w & 1) << 11)
                       | ((md.x & 1) << 12) | ((md.y & 1) << 13) | ((md.z & 1) << 14) | ((md.w & 1) << 15);
        msk16[t] = bits;
    }

    // ---- score at t=0 for this thread's 16 (batch m, state j) cells
    float sc0v[4][4];
    #pragma unroll
    for (int mt = 0; mt < 4; ++mt) {
        const int j0 = 64 * w + 16 * mt + 4 * grp;
        const float4 f0 = *(const float4*)&feats[((size_t)b0 + m) * T + j0];
        const float4 st = *(const float4*)&start_t[j0];
        sc0v[mt][0] = st.x + f0.x; sc0v[mt][1] = st.y + f0.y;
        sc0v[mt][2] = st.z + f0.z; sc0v[mt][3] = st.w + f0.w;
    }

    // ---- gold-score partials: thread (batch tid&15, chunk tid>>4) covers 32 time steps
    {
        const int mg = tid & 15, chunk = tid >> 4;
        const int t0 = chunk * 32;
        float g = 0.f, mc = 0.f;
        int tgp = (t0 > 0) ? tags[(size_t)(t0 - 1) * B + b0 + mg] : 0;
        #pragma unroll
        for (int tt = 0; tt < 32; ++tt) {
            const int t = t0 + tt;
            const int tg = tags[(size_t)t * B + b0 + mg];
            const int mk = mask[(size_t)t * B + b0 + mg];
            const float emit = feats[((size_t)t * B + b0 + mg) * T + tg];
            mc += (float)mk;
            if (t == 0) g += start_t[tg] + emit;
            else        g += mk ? (emit + trans[(size_t)tgp * T + tg]) : 0.f;
            tgp = tg;
        }
        redg[mg][chunk] = g;
        redm[mg][chunk] = mc;
    }

    // ---- E^T fragments in registers (A operand) — verified mapping (R9)
    h8 E[4][8];
    #pragma unroll
    for (int mt = 0; mt < 4; ++mt) {
        const int j = 64 * w + 16 * mt + m;
        #pragma unroll
        for (int kt = 0; kt < 8; ++kt) {
            const int kb = kt * 32 + grp * 8;
            h8 v;
            #pragma unroll
            for (int i = 0; i < 8; ++i)
                v[i] = (__fp16)EXP2(LOG2E * trans[(size_t)(kb + i) * T + j]);
            E[mt][kt] = v;
        }
    }

    // ---- per-batch max of sc0 (wave level)
    {
        float lm = sc0v[0][0];
        #pragma unroll
        for (int mt = 0; mt < 4; ++mt)
            #pragma unroll
            for (int p = 0; p < 4; ++p) lm = fmaxf(lm, sc0v[mt][p]);
        lm = fmaxf(lm, __shfl_xor(lm, 16, 64));
        lm = fmaxf(lm, __shfl_xor(lm, 32, 64));
        if (grp == 0) redi[m][w] = lm;
    }

    __syncthreads();   // full drain once: tiles 1..4 landed, init LDS visible

    if (tid < NB) {
        float g = 0.f, mc = 0.f;
        #pragma unroll
        for (int c = 0; c < 16; ++c) { g += redg[tid][c]; mc += redm[tid][c]; }
        const int se = (int)mc - 1;
        goldv[tid] = g + end_t[tags[(size_t)se * B + b0 + tid]];
    }

    // ---- linear-state init: q = 2^(sc0*log2e - A_m)
    const float4 ri = *(const float4*)&redi[m][0];
    const float gmax0 = fmaxf(fmaxf(ri.x, ri.y), fmaxf(ri.z, ri.w));
    int A = (int)ceilf(gmax0 * LOG2E) + 10;

    float qv[4][4];
    {
        float lmax = 0.f;
        #pragma unroll
        for (int mt = 0; mt < 4; ++mt)
            #pragma unroll
            for (int p = 0; p < 4; ++p) {
                const float x = EXP2(fmaf(sc0v[mt][p], LOG2E, (float)(-A)));
                qv[mt][p] = x;
                lmax = fmaxf(lmax, x);
            }
        #pragma unroll
        for (int mt = 0; mt < 4; ++mt) {
            const int ktw = 2 * w + (mt >> 1);
            const int lp  = (((2 * mt + (grp >> 1)) & 3) << 4) | m;
            const int i0  = 4 * (grp & 1);
            int2 wv;
            wv.x = __builtin_bit_cast(int, (h2v)__builtin_amdgcn_cvt_pkrtz(qv[mt][0], qv[mt][1]));
            wv.y = __builtin_bit_cast(int, (h2v)__builtin_amdgcn_cvt_pkrtz(qv[mt][2], qv[mt][3]));
            *(int2*)&qfrag[0][ktw][lp][i0] = wv;
        }
        lmax = fmaxf(lmax, __shfl_xor(lmax, 16, 64));
        lmax = fmaxf(lmax, __shfl_xor(lmax, 32, 64));
        if (grp == 0) redq[0][m][w] = lmax;
    }

    // ---- F(1) into registers (tiles landed; exp off the recursion path)
    float Freg[4][4];
    #pragma unroll
    for (int mt = 0; mt < 4; ++mt) {
        const int j0 = 64 * w + 16 * mt + 4 * grp;
        const float4 fv = *(const float4*)&ftile[1][m][j0];
        Freg[mt][0] = EXP2(fv.x * LOG2E); Freg[mt][1] = EXP2(fv.y * LOG2E);
        Freg[mt][2] = EXP2(fv.z * LOG2E); Freg[mt][3] = EXP2(fv.w * LOG2E);
    }

    BAR();   // qfrag[0]/redq[0] visible; DMA queue empty (drained at syncthreads)

    // ==== main recursion: one MFMA step advances all 16 batches ====
    for (int t = 1; t < S; ++t) {
        const int cur = (t - 1) & 1, nxt = t & 1;

        // step scale (early, off-path): k from previous per-batch max
        const float4 rq = *(const float4*)&redq[cur][m][0];
        const int mbits = msk16[t];
        const float gm = fmaxf(fmaxf(rq.x, rq.y), fmaxf(rq.z, rq.w));
        const int k = ((__builtin_bit_cast(int, gm) >> 23) & 0xff) - 117;  // floor(log2 gm)+10
        const float s2k = __builtin_bit_cast(float, (127 - k) << 23);      // 2^-k exact
        float Fs[4][4];
        #pragma unroll
        for (int mt = 0; mt < 4; ++mt)
            #pragma unroll
            for (int p = 0; p < 4; ++p) Fs[mt][p] = Freg[mt][p] * s2k;

        // issue DMA tile t+4
        if (t <= S - 5) {
            #pragma unroll
            for (int qq = 0; qq < 4; ++qq) {
                const int mr = 4 * qq + w;
                const float* src = feats + ((size_t)(t + 4) * B + b0 + mr) * T + l * 4;
                __builtin_amdgcn_global_load_lds((const AS1 void*)src,
                                                 (AS3 void*)&ftile[(t + 4) & 3][mr][l * 4], 16, 0, 0);
            }
        }

        // B-operand (contiguous lane*16B) + MFMA, K split in two halves (depth 4)
        f32x4 z = {0.f, 0.f, 0.f, 0.f};
        f32x4 a0A = z, a1A = z, a2A = z, a3A = z, a0B = z, a1B = z, a2B = z, a3B = z;
        {
            h8 bf0 = *(const h8*)&qfrag[cur][0][l][0];
            h8 bf1 = *(const h8*)&qfrag[cur][1][l][0];
            h8 bf2 = *(const h8*)&qfrag[cur][2][l][0];
            h8 bf3 = *(const h8*)&qfrag[cur][3][l][0];
            a0A = __builtin_amdgcn_mfma_f32_16x16x32_f16(E[0][0], bf0, a0A, 0, 0, 0);
            a1A = __builtin_amdgcn_mfma_f32_16x16x32_f16(E[1][0], bf0, a1A, 0, 0, 0);
            a2A = __builtin_amdgcn_mfma_f32_16x16x32_f16(E[2][0], bf0, a2A, 0, 0, 0);
            a3A = __builtin_amdgcn_mfma_f32_16x16x32_f16(E[3][0], bf0, a3A, 0, 0, 0);
            a0A = __builtin_amdgcn_mfma_f32_16x16x32_f16(E[0][1], bf1, a0A, 0, 0, 0);
            a1A = __builtin_amdgcn_mfma_f32_16x16x32_f16(E[1][1], bf1, a1A, 0, 0, 0);
            a2A = __builtin_amdgcn_mfma_f32_16x16x32_f16(E[2][1], bf1, a2A, 0, 0, 0);
            a3A = __builtin_amdgcn_mfma_f32_16x16x32_f16(E[3][1], bf1, a3A, 0, 0, 0);
            a0A = __builtin_amdgcn_mfma_f32_16x16x32_f16(E[0][2], bf2, a0A, 0, 0, 0);
            a1A = __builtin_amdgcn_mfma_f32_16x16x32_f16(E[1][2], bf2, a1A, 0, 0, 0);
            a2A = __builtin_amdgcn_mfma_f32_16x16x32_f16(E[2][2], bf2, a2A, 0, 0, 0);
            a3A = __builtin_amdgcn_mfma_f32_16x16x32_f16(E[3][2], bf2, a3A, 0, 0, 0);
            a0A = __builtin_amdgcn_mfma_f32_16x16x32_f16(E[0][3], bf3, a0A, 0, 0, 0);
            a1A = __builtin_amdgcn_mfma_f32_16x16x32_f16(E[1][3], bf3, a1A, 0, 0, 0);
            a2A = __builtin_amdgcn_mfma_f32_16x16x32_f16(E[2][3], bf3, a2A, 0, 0, 0);
            a3A = __builtin_amdgcn_mfma_f32_16x16x32_f16(E[3][3], bf3, a3A, 0, 0, 0);
        }
        {
            h8 bf4 = *(const h8*)&qfrag[cur][4][l][0];
            h8 bf5 = *(const h8*)&qfrag[cur][5][l][0];
            h8 bf6 = *(const h8*)&qfrag[cur][6][l][0];
            h8 bf7 = *(const h8*)&qfrag[cur][7][l][0];
            a0B = __builtin_amdgcn_mfma_f32_16x16x32_f16(E[0][4], bf4, a0B, 0, 0, 0);
            a1B = __builtin_amdgcn_mfma_f32_16x16x32_f16(E[1][4], bf4, a1B, 0, 0, 0);
            a2B = __builtin_amdgcn_mfma_f32_16x16x32_f16(E[2][4], bf4, a2B, 0, 0, 0);
            a3B = __builtin_amdgcn_mfma_f32_16x16x32_f16(E[3][4], bf4, a3B, 0, 0, 0);
            a0B = __builtin_amdgcn_mfma_f32_16x16x32_f16(E[0][5], bf5, a0B, 0, 0, 0);
            a1B = __builtin_amdgcn_mfma_f32_16x16x32_f16(E[1][5], bf5, a1B, 0, 0, 0);
            a2B = __builtin_amdgcn_mfma_f32_16x16x32_f16(E[2][5], bf5, a2B, 0, 0, 0);
            a3B = __builtin_amdgcn_mfma_f32_16x16x32_f16(E[3][5], bf5, a3B, 0, 0, 0);
            a0B = __builtin_amdgcn_mfma_f32_16x16x32_f16(E[0][6], bf6, a0B, 0, 0, 0);
            a1B = __builtin_amdgcn_mfma_f32_16x16x32_f16(E[1][6], bf6, a1B, 0, 0, 0);
            a2B = __builtin_amdgcn_mfma_f32_16x16x32_f16(E[2][6], bf6, a2B, 0, 0, 0);
            a3B = __builtin_amdgcn_mfma_f32_16x16x32_f16(E[3][6], bf6, a3B, 0, 0, 0);
            a0B = __builtin_amdgcn_mfma_f32_16x16x32_f16(E[0][7], bf7, a0B, 0, 0, 0);
            a1B = __builtin_amdgcn_mfma_f32_16x16x32_f16(E[1][7], bf7, a1B, 0, 0, 0);
            a2B = __builtin_amdgcn_mfma_f32_16x16x32_f16(E[2][7], bf7, a2B, 0, 0, 0);
            a3B = __builtin_amdgcn_mfma_f32_16x16x32_f16(E[3][7], bf7, a3B, 0, 0, 0);
        }

        // F(t+1) prefetch: raw read + exp2, interleaves with MFMA (separate pipes)
        if (t < S - 1) {
            #pragma unroll
            for (int mt = 0; mt < 4; ++mt) {
                const int j0 = 64 * w + 16 * mt + 4 * grp;
                const float4 fv = *(const float4*)&ftile[(t + 1) & 3][m][j0];
                Freg[mt][0] = EXP2(fv.x * LOG2E); Freg[mt][1] = EXP2(fv.y * LOG2E);
                Freg[mt][2] = EXP2(fv.z * LOG2E); Freg[mt][3] = EXP2(fv.w * LOG2E);
            }
        }

        // elementwise: q' = D * exp(ft) * 2^-k (fast path: mask all ones)
        const f32x4 acc0 = a0A + a0B, acc1 = a1A + a1B, acc2 = a2A + a2B, acc3 = a3A + a3B;
        float lmax = 0.f;
        const int mbu = __builtin_amdgcn_readfirstlane(mbits);
        if (__builtin_expect(mbu == 0xffff, 1)) {
            #pragma unroll
            for (int mt = 0; mt < 4; ++mt) {
                const f32x4 ac = (mt == 0) ? acc0 : (mt == 1) ? acc1 : (mt == 2) ? acc2 : acc3;
                #pragma unroll
                for (int p = 0; p < 4; ++p) {
                    const float x = ac[p] * Fs[mt][p];
                    qv[mt][p] = x;
                    lmax = fmaxf(lmax, x);
                }
            }
        } else {
            const int mskb = (mbits >> m) & 1;
            #pragma unroll
            for (int mt = 0; mt < 4; ++mt) {
                const f32x4 ac = (mt == 0) ? acc0 : (mt == 1) ? acc1 : (mt == 2) ? acc2 : acc3;
                #pragma unroll
                for (int p = 0; p < 4; ++p) {
                    const float x = mskb ? (ac[p] * Fs[mt][p]) : mul2n(qv[mt][p], -k);
                    qv[mt][p] = x;
                    lmax = fmaxf(lmax, x);
                }
            }
        }
        A += k;

        // pack q' into B-fragment order + per-batch max for next step's k
        #pragma unroll
        for (int mt = 0; mt < 4; ++mt) {
            const int ktw = 2 * w + (mt >> 1);
            const int lp  = (((2 * mt + (grp >> 1)) & 3) << 4) | m;
            const int i0  = 4 * (grp & 1);
            int2 wv;
            wv.x = __builtin_bit_cast(int, (h2v)__builtin_amdgcn_cvt_pkrtz(qv[mt][0], qv[mt][1]));
            wv.y = __builtin_bit_cast(int, (h2v)__builtin_amdgcn_cvt_pkrtz(qv[mt][2], qv[mt][3]));
            *(int2*)&qfrag[nxt][ktw][lp][i0] = wv;
        }
        lmax = fmaxf(lmax, __shfl_xor(lmax, 16, 64));
        lmax = fmaxf(lmax, __shfl_xor(lmax, 32, 64));
        if (grp == 0) redq[nxt][m][w] = lmax;

        // counted drain: guarantee tile t+2 landed at this barrier (F(t+2) read next iter)
        if (t <= S - 5)      asm volatile("s_waitcnt vmcnt(8)" ::: "memory");
        else if (t == S - 4) asm volatile("s_waitcnt vmcnt(4)" ::: "memory");
        else                 asm volatile("s_waitcnt vmcnt(0)" ::: "memory");
        BAR();   // the only barrier per step
    }

    // ---- finalize: score = (log2 q + A_m)*ln2; forward_m = LSE_j(score + end)
    float u[4][4];
    float lmax2 = -3.0e38f;
    #pragma unroll
    for (int mt = 0; mt < 4; ++mt) {
        const int j0 = 64 * w + 16 * mt + 4 * grp;
        const float4 ev = *(const float4*)&endf[j0];
        const float es[4] = {ev.x, ev.y, ev.z, ev.w};
        #pragma unroll
        for (int p = 0; p < 4; ++p) {
            const float uu = LOG2F(qv[mt][p]) + (float)A + es[p] * LOG2E;
            u[mt][p] = uu;
            lmax2 = fmaxf(lmax2, uu);
        }
    }
    lmax2 = fmaxf(lmax2, __shfl_xor(lmax2, 16, 64));
    lmax2 = fmaxf(lmax2, __shfl_xor(lmax2, 32, 64));
    if (grp == 0) redF[m][w] = lmax2;
    BAR();
    {
        const float4 rf = *(const float4*)&redF[m][0];
        const float M = fmaxf(fmaxf(rf.x, rf.y), fmaxf(rf.z, rf.w));
        float se = 0.f;
        #pragma unroll
        for (int mt = 0; mt < 4; ++mt)
            #pragma unroll
            for (int p = 0; p < 4; ++p) se += EXP2(u[mt][p] - M);
        se += __shfl_xor(se, 16, 64);
        se += __shfl_xor(se, 32, 64);
        if (grp == 0) redS[m][w] = se;
    }
    BAR();
    if (tid < NB) {
        const float4 rf = *(const float4*)&redF[tid][0];
        const float4 rs = *(const float4*)&redS[tid][0];
        const float M = fmaxf(fmaxf(rf.x, rf.y), fmaxf(rf.z, rf.w));
        out[b0 + tid] = (M + LOG2F(rs.x + rs.y + rs.z + rs.w)) * LN2 - goldv[tid];
    }
}

extern "C" void kernel_launch(void* const* d_in, const int* in_sizes, int n_in,
                              void* d_out, int out_size, void* d_ws, size_t ws_size,
                              hipStream_t stream) {
    const float* feats  = (const float*)d_in[0];
    const int*   tags   = (const int*)d_in[1];
    const int*   mask   = (const int*)d_in[2];
    const float* startt = (const float*)d_in[3];
    const float* endt   = (const float*)d_in[4];
    const float* transt = (const float*)d_in[5];
    float* out = (float*)d_out;
    crf_fwd<<<dim3(B / NB), dim3(NTH), 0, stream>>>(feats, tags, mask, startt, endt, transt, out);
}

// Round 11
// 389.079 us; speedup vs baseline: 1.2758x; 1.2758x over previous
//
#include <hip/hip_runtime.h>
#include <math.h>

#define S 512
#define B 128
#define T 256
#define NB 16          // batches per block
#define NTH 512        // 8 waves: wave w8 owns output states [32*w8, 32*w8+32)
#define FR 260         // ftile row stride (floats)
#define LOG2E 1.44269504f
#define LN2 0.69314718f

typedef __fp16 h2v __attribute__((ext_vector_type(2)));
typedef __fp16 h8 __attribute__((ext_vector_type(8)));
typedef float f32x4 __attribute__((ext_vector_type(4)));

#if __has_builtin(__builtin_amdgcn_exp2f)
#define EXP2(x) __builtin_amdgcn_exp2f(x)
#else
#define EXP2(x) exp2f(x)
#endif
#if __has_builtin(__builtin_amdgcn_logf)
#define LOG2F(x) __builtin_amdgcn_logf(x)
#else
#define LOG2F(x) __log2f(x)
#endif

#define AS1 __attribute__((address_space(1)))
#define AS3 __attribute__((address_space(3)))
// LDS-drain barrier only (DMA ring stays in flight; counted vmcnt separately)
#define BAR() do { asm volatile("s_waitcnt lgkmcnt(0)" ::: "memory"); __builtin_amdgcn_s_barrier(); } while (0)

// exact x * 2^n (n in [-126,127])
__device__ __forceinline__ float mul2n(float x, int n) {
    return x * __builtin_bit_cast(float, (n + 127) << 23);
}

// max over lanes {l, l^16, l^32, l^48}; result valid in lanes 0..15.
// permlane*_swap returns both outputs; fmax over BOTH hedges the .x/.y semantics
// (for lanes<16 one of them is the own value -> idempotent under max).
__device__ __forceinline__ float cross_max(float x) {
#if __has_builtin(__builtin_amdgcn_permlane32_swap) && __has_builtin(__builtin_amdgcn_permlane16_swap)
    int xi = __builtin_bit_cast(int, x);
    auto s32 = __builtin_amdgcn_permlane32_swap(xi, xi, false, false);
    float y = fmaxf(x, fmaxf(__builtin_bit_cast(float, (int)s32[0]),
                             __builtin_bit_cast(float, (int)s32[1])));
    int yi = __builtin_bit_cast(int, y);
    auto s16 = __builtin_amdgcn_permlane16_swap(yi, yi, false, false);
    return fmaxf(y, fmaxf(__builtin_bit_cast(float, (int)s16[0]),
                          __builtin_bit_cast(float, (int)s16[1])));
#else
    x = fmaxf(x, __shfl_xor(x, 32, 64));
    x = fmaxf(x, __shfl_xor(x, 16, 64));
    return x;
#endif
}

__global__ __launch_bounds__(NTH, 2) void crf_fwd(
    const float* __restrict__ feats,
    const int*   __restrict__ tags,
    const int*   __restrict__ mask,
    const float* __restrict__ start_t,
    const float* __restrict__ end_t,
    const float* __restrict__ trans,
    float*       __restrict__ out)
{
    const int tid = threadIdx.x;
    const int l   = tid & 63;
    const int w8  = tid >> 6;     // wave 0..7
    const int m   = l & 15;       // batch (MFMA M/N lane mapping)
    const int grp = l >> 4;       // 0..3
    const int b0  = blockIdx.x * NB;

    __shared__ __attribute__((aligned(16))) __fp16 qfrag[2][8][64][8];   // 16 KB, B-frag order
    __shared__ __attribute__((aligned(16))) float ftile[4][NB][FR];      // 65 KB DMA ring
    __shared__ int msk16[S];
    __shared__ __attribute__((aligned(16))) float redq[2][NB][8];
    __shared__ __attribute__((aligned(16))) float redi[NB][8];
    __shared__ __attribute__((aligned(16))) float redF[NB][8];
    __shared__ __attribute__((aligned(16))) float redS[NB][8];
    __shared__ float redg[NB][32], redm[NB][32];
    __shared__ float goldv[NB];
    __shared__ __attribute__((aligned(16))) float endf[T];

    // ---- prime DMA ring: tiles 1..4, each wave loads its 2 batch-rows
    #pragma unroll
    for (int tn = 1; tn <= 4; ++tn) {
        #pragma unroll
        for (int qq = 0; qq < 2; ++qq) {
            const int mr = 2 * w8 + qq;
            const float* src = feats + ((size_t)tn * B + b0 + mr) * T + l * 4;
            __builtin_amdgcn_global_load_lds((const AS1 void*)src,
                                             (AS3 void*)&ftile[tn & 3][mr][l * 4], 16, 0, 0);
        }
    }

    if (tid < T) endf[tid] = end_t[tid];

    // ---- mask bits: msk16[t] bit m = mask[t][b0+m] (512 threads = S)
    {
        const int t = tid;
        const int4 ma = *(const int4*)&mask[(size_t)t * B + b0];
        const int4 mb = *(const int4*)&mask[(size_t)t * B + b0 + 4];
        const int4 mcq = *(const int4*)&mask[(size_t)t * B + b0 + 8];
        const int4 md = *(const int4*)&mask[(size_t)t * B + b0 + 12];
        msk16[t] = (ma.x & 1) | ((ma.y & 1) << 1) | ((ma.z & 1) << 2) | ((ma.w & 1) << 3)
                 | ((mb.x & 1) << 4) | ((mb.y & 1) << 5) | ((mb.z & 1) << 6) | ((mb.w & 1) << 7)
                 | ((mcq.x & 1) << 8) | ((mcq.y & 1) << 9) | ((mcq.z & 1) << 10) | ((mcq.w & 1) << 11)
                 | ((md.x & 1) << 12) | ((md.y & 1) << 13) | ((md.z & 1) << 14) | ((md.w & 1) << 15);
    }

    // ---- score at t=0 for this thread's 8 (batch m, state j) cells
    float sc0v[2][4];
    #pragma unroll
    for (int mt = 0; mt < 2; ++mt) {
        const int j0 = 32 * w8 + 16 * mt + 4 * grp;
        const float4 f0 = *(const float4*)&feats[((size_t)b0 + m) * T + j0];
        const float4 st = *(const float4*)&start_t[j0];
        sc0v[mt][0] = st.x + f0.x; sc0v[mt][1] = st.y + f0.y;
        sc0v[mt][2] = st.z + f0.z; sc0v[mt][3] = st.w + f0.w;
    }

    // ---- gold-score partials: thread (batch tid&15, chunk tid>>4) covers 16 time steps
    {
        const int mg = tid & 15, chunk = tid >> 4;   // chunk 0..31
        const int t0 = chunk * 16;
        float g = 0.f, mc = 0.f;
        int tgp = (t0 > 0) ? tags[(size_t)(t0 - 1) * B + b0 + mg] : 0;
        #pragma unroll
        for (int tt = 0; tt < 16; ++tt) {
            const int t = t0 + tt;
            const int tg = tags[(size_t)t * B + b0 + mg];
            const int mk = mask[(size_t)t * B + b0 + mg];
            const float emit = feats[((size_t)t * B + b0 + mg) * T + tg];
            mc += (float)mk;
            if (t == 0) g += start_t[tg] + emit;
            else        g += mk ? (emit + trans[(size_t)tgp * T + tg]) : 0.f;
            tgp = tg;
        }
        redg[mg][chunk] = g;
        redm[mg][chunk] = mc;
    }

    // ---- E^T fragments (A operand), R9-verified mapping; rows j = 32w8+16mt+m
    h8 E[2][8];
    #pragma unroll
    for (int mt = 0; mt < 2; ++mt) {
        const int j = 32 * w8 + 16 * mt + m;
        #pragma unroll
        for (int kt = 0; kt < 8; ++kt) {
            const int kb = kt * 32 + grp * 8;
            h8 v;
            #pragma unroll
            for (int i = 0; i < 8; ++i)
                v[i] = (__fp16)EXP2(LOG2E * trans[(size_t)(kb + i) * T + j]);
            E[mt][kt] = v;
        }
    }

    // ---- per-batch max of sc0
    {
        float lm = sc0v[0][0];
        #pragma unroll
        for (int mt = 0; mt < 2; ++mt)
            #pragma unroll
            for (int p = 0; p < 4; ++p) lm = fmaxf(lm, sc0v[mt][p]);
        lm = cross_max(lm);
        if (l < 16) redi[m][w8] = lm;
    }

    __syncthreads();   // full drain once: tiles 1..4 landed, init LDS visible

    if (tid < NB) {
        float g = 0.f, mc = 0.f;
        #pragma unroll
        for (int c = 0; c < 32; ++c) { g += redg[tid][c]; mc += redm[tid][c]; }
        goldv[tid] = g + end_t[tags[(size_t)((int)mc - 1) * B + b0 + tid]];
    }

    // ---- linear-state init: q = 2^(sc0*log2e - A_m), per-batch A_m so max ~= 2^-10
    const float4 ria = *(const float4*)&redi[m][0];
    const float4 rib = *(const float4*)&redi[m][4];
    const float gmax0 = fmaxf(fmaxf(fmaxf(ria.x, ria.y), fmaxf(ria.z, ria.w)),
                              fmaxf(fmaxf(rib.x, rib.y), fmaxf(rib.z, rib.w)));
    int A = (int)ceilf(gmax0 * LOG2E) + 10;

    float qv[2][4];
    {
        float lmax = 0.f;
        #pragma unroll
        for (int mt = 0; mt < 2; ++mt)
            #pragma unroll
            for (int p = 0; p < 4; ++p) {
                const float x = EXP2(fmaf(sc0v[mt][p], LOG2E, (float)(-A)));
                qv[mt][p] = x;
                lmax = fmaxf(lmax, x);
            }
        #pragma unroll
        for (int mt = 0; mt < 2; ++mt) {
            const int lp = (((2 * mt + (grp >> 1)) & 3) << 4) | m;
            const int i0 = 4 * (grp & 1);
            int2 wv;
            wv.x = __builtin_bit_cast(int, (h2v)__builtin_amdgcn_cvt_pkrtz(qv[mt][0], qv[mt][1]));
            wv.y = __builtin_bit_cast(int, (h2v)__builtin_amdgcn_cvt_pkrtz(qv[mt][2], qv[mt][3]));
            *(int2*)&qfrag[0][w8][lp][i0] = wv;
        }
        lmax = cross_max(lmax);
        if (l < 16) redq[0][m][w8] = lmax;
    }

    // ---- F(1) into registers (exp off the recursion path)
    float Freg[2][4];
    #pragma unroll
    for (int mt = 0; mt < 2; ++mt) {
        const int j0 = 32 * w8 + 16 * mt + 4 * grp;
        const float4 fv = *(const float4*)&ftile[1][m][j0];
        Freg[mt][0] = EXP2(fv.x * LOG2E); Freg[mt][1] = EXP2(fv.y * LOG2E);
        Freg[mt][2] = EXP2(fv.z * LOG2E); Freg[mt][3] = EXP2(fv.w * LOG2E);
    }

    BAR();   // qfrag[0]/redq[0] visible

    // ==== main recursion: one MFMA step advances all 16 batches ====
    for (int t = 1; t < S; ++t) {
        const int cur = (t - 1) & 1, nxt = t & 1;

        // step scale (early, off-path): per-batch k from previous step's max
        const float4 rqa = *(const float4*)&redq[cur][m][0];
        const float4 rqb = *(const float4*)&redq[cur][m][4];
        const int mbits = msk16[t];
        const float gm = fmaxf(fmaxf(fmaxf(rqa.x, rqa.y), fmaxf(rqa.z, rqa.w)),
                               fmaxf(fmaxf(rqb.x, rqb.y), fmaxf(rqb.z, rqb.w)));
        const int k = ((__builtin_bit_cast(int, gm) >> 23) & 0xff) - 117;  // floor(log2 gm)+10
        const float s2k = __builtin_bit_cast(float, (127 - k) << 23);      // 2^-k exact
        float Fs[2][4];
        #pragma unroll
        for (int mt = 0; mt < 2; ++mt)
            #pragma unroll
            for (int p = 0; p < 4; ++p) Fs[mt][p] = Freg[mt][p] * s2k;

        // issue DMA tile t+4 (2 rows per wave)
        if (t <= S - 5) {
            #pragma unroll
            for (int qq = 0; qq < 2; ++qq) {
                const int mr = 2 * w8 + qq;
                const float* src = feats + ((size_t)(t + 4) * B + b0 + mr) * T + l * 4;
                __builtin_amdgcn_global_load_lds((const AS1 void*)src,
                                                 (AS3 void*)&ftile[(t + 4) & 3][mr][l * 4], 16, 0, 0);
            }
        }

        // B-operand reads + MFMA: 2 j-tiles x K=256 -> 16 MFMAs, 4 chains of 4
        h8 bf0 = *(const h8*)&qfrag[cur][0][l][0];
        h8 bf1 = *(const h8*)&qfrag[cur][1][l][0];
        h8 bf2 = *(const h8*)&qfrag[cur][2][l][0];
        h8 bf3 = *(const h8*)&qfrag[cur][3][l][0];
        h8 bf4 = *(const h8*)&qfrag[cur][4][l][0];
        h8 bf5 = *(const h8*)&qfrag[cur][5][l][0];
        h8 bf6 = *(const h8*)&qfrag[cur][6][l][0];
        h8 bf7 = *(const h8*)&qfrag[cur][7][l][0];
        f32x4 z = {0.f, 0.f, 0.f, 0.f};
        f32x4 aA = z, aB = z, cA = z, cB = z;
        __builtin_amdgcn_s_setprio(1);
        aA = __builtin_amdgcn_mfma_f32_16x16x32_f16(E[0][0], bf0, aA, 0, 0, 0);
        cA = __builtin_amdgcn_mfma_f32_16x16x32_f16(E[1][0], bf0, cA, 0, 0, 0);
        aB = __builtin_amdgcn_mfma_f32_16x16x32_f16(E[0][4], bf4, aB, 0, 0, 0);
        cB = __builtin_amdgcn_mfma_f32_16x16x32_f16(E[1][4], bf4, cB, 0, 0, 0);
        aA = __builtin_amdgcn_mfma_f32_16x16x32_f16(E[0][1], bf1, aA, 0, 0, 0);
        cA = __builtin_amdgcn_mfma_f32_16x16x32_f16(E[1][1], bf1, cA, 0, 0, 0);
        aB = __builtin_amdgcn_mfma_f32_16x16x32_f16(E[0][5], bf5, aB, 0, 0, 0);
        cB = __builtin_amdgcn_mfma_f32_16x16x32_f16(E[1][5], bf5, cB, 0, 0, 0);
        aA = __builtin_amdgcn_mfma_f32_16x16x32_f16(E[0][2], bf2, aA, 0, 0, 0);
        cA = __builtin_amdgcn_mfma_f32_16x16x32_f16(E[1][2], bf2, cA, 0, 0, 0);
        aB = __builtin_amdgcn_mfma_f32_16x16x32_f16(E[0][6], bf6, aB, 0, 0, 0);
        cB = __builtin_amdgcn_mfma_f32_16x16x32_f16(E[1][6], bf6, cB, 0, 0, 0);
        aA = __builtin_amdgcn_mfma_f32_16x16x32_f16(E[0][3], bf3, aA, 0, 0, 0);
        cA = __builtin_amdgcn_mfma_f32_16x16x32_f16(E[1][3], bf3, cA, 0, 0, 0);
        aB = __builtin_amdgcn_mfma_f32_16x16x32_f16(E[0][7], bf7, aB, 0, 0, 0);
        cB = __builtin_amdgcn_mfma_f32_16x16x32_f16(E[1][7], bf7, cB, 0, 0, 0);
        __builtin_amdgcn_s_setprio(0);

        // F(t+1) prefetch: interleaves with MFMA (separate pipes)
        if (t < S - 1) {
            #pragma unroll
            for (int mt = 0; mt < 2; ++mt) {
                const int j0 = 32 * w8 + 16 * mt + 4 * grp;
                const float4 fv = *(const float4*)&ftile[(t + 1) & 3][m][j0];
                Freg[mt][0] = EXP2(fv.x * LOG2E); Freg[mt][1] = EXP2(fv.y * LOG2E);
                Freg[mt][2] = EXP2(fv.z * LOG2E); Freg[mt][3] = EXP2(fv.w * LOG2E);
            }
        }

        // elementwise: q' = D * exp(ft) * 2^-k (fast path: mask all ones)
        const f32x4 acc0 = aA + aB, acc1 = cA + cB;
        float lmax = 0.f;
        const int mbu = __builtin_amdgcn_readfirstlane(mbits);
        if (__builtin_expect(mbu == 0xffff, 1)) {
            #pragma unroll
            for (int p = 0; p < 4; ++p) {
                const float x0 = acc0[p] * Fs[0][p];
                const float x1 = acc1[p] * Fs[1][p];
                qv[0][p] = x0; qv[1][p] = x1;
                lmax = fmaxf(lmax, fmaxf(x0, x1));
            }
        } else {
            const int mskb = (mbits >> m) & 1;
            #pragma unroll
            for (int mt = 0; mt < 2; ++mt)
                #pragma unroll
                for (int p = 0; p < 4; ++p) {
                    const f32x4 ac = (mt == 0) ? acc0 : acc1;
                    const float x = mskb ? (ac[p] * Fs[mt][p]) : mul2n(qv[mt][p], -k);
                    qv[mt][p] = x;
                    lmax = fmaxf(lmax, x);
                }
        }
        A += k;

        // pack q' into B-fragment order (kt = w8) + per-batch max via permlane
        #pragma unroll
        for (int mt = 0; mt < 2; ++mt) {
            const int lp = (((2 * mt + (grp >> 1)) & 3) << 4) | m;
            const int i0 = 4 * (grp & 1);
            int2 wv;
            wv.x = __builtin_bit_cast(int, (h2v)__builtin_amdgcn_cvt_pkrtz(qv[mt][0], qv[mt][1]));
            wv.y = __builtin_bit_cast(int, (h2v)__builtin_amdgcn_cvt_pkrtz(qv[mt][2], qv[mt][3]));
            *(int2*)&qfrag[nxt][w8][lp][i0] = wv;
        }
        lmax = cross_max(lmax);
        if (l < 16) redq[nxt][m][w8] = lmax;

        if (t <= S - 5) asm volatile("s_waitcnt vmcnt(4)" ::: "memory");  // tile t+2 landed
        else            asm volatile("s_waitcnt vmcnt(0)" ::: "memory");
        BAR();   // the only barrier per step
    }

    // ---- finalize: score = (log2 q + A_m)*ln2; forward_m = LSE_j(score + end)
    float u[2][4];
    float lmax2 = -3.0e38f;
    #pragma unroll
    for (int mt = 0; mt < 2; ++mt) {
        const int j0 = 32 * w8 + 16 * mt + 4 * grp;
        const float4 ev = *(const float4*)&endf[j0];
        const float es[4] = {ev.x, ev.y, ev.z, ev.w};
        #pragma unroll
        for (int p = 0; p < 4; ++p) {
            const float uu = LOG2F(qv[mt][p]) + (float)A + es[p] * LOG2E;
            u[mt][p] = uu;
            lmax2 = fmaxf(lmax2, uu);
        }
    }
    lmax2 = cross_max(lmax2);
    if (l < 16) redF[m][w8] = lmax2;
    BAR();
    {
        const float4 rfa = *(const float4*)&redF[m][0];
        const float4 rfb = *(const float4*)&redF[m][4];
        const float M = fmaxf(fmaxf(fmaxf(rfa.x, rfa.y), fmaxf(rfa.z, rfa.w)),
                              fmaxf(fmaxf(rfb.x, rfb.y), fmaxf(rfb.z, rfb.w)));
        float se = 0.f;
        #pragma unroll
        for (int mt = 0; mt < 2; ++mt)
            #pragma unroll
            for (int p = 0; p < 4; ++p) se += EXP2(u[mt][p] - M);
        se += __shfl_xor(se, 16, 64);   // exact sum: shfl (permlane hedge not sum-safe)
        se += __shfl_xor(se, 32, 64);
        if (l < 16) redS[m][w8] = se;
    }
    BAR();
    if (tid < NB) {
        const float4 rfa = *(const float4*)&redF[tid][0];
        const float4 rfb = *(const float4*)&redF[tid][4];
        const float M = fmaxf(fmaxf(fmaxf(rfa.x, rfa.y), fmaxf(rfa.z, rfa.w)),
                              fmaxf(fmaxf(rfb.x, rfb.y), fmaxf(rfb.z, rfb.w)));
        float ssum = 0.f;
        #pragma unroll
        for (int c = 0; c < 8; ++c) ssum += redS[tid][c];
        out[b0 + tid] = (M + LOG2F(ssum)) * LN2 - goldv[tid];
    }
}

extern "C" void kernel_launch(void* const* d_in, const int* in_sizes, int n_in,
                              void* d_out, int out_size, void* d_ws, size_t ws_size,
                              hipStream_t stream) {
    const float* feats  = (const float*)d_in[0];
    const int*   tags   = (const int*)d_in[1];
    const int*   mask   = (const int*)d_in[2];
    const float* startt = (const float*)d_in[3];
    const float* endt   = (const float*)d_in[4];
    const float* transt = (const float*)d_in[5];
    float* out = (float*)d_out;
    crf_fwd<<<dim3(B / NB), dim3(NTH), 0, stream>>>(feats, tags, mask, startt, endt, transt, out);
}